// Round 4
// baseline (152.827 us; speedup 1.0000x reference)
//
#include <hip/hip_runtime.h>
#include <math.h>

// 256-point FFT = 16x16 four-step Cooley-Tukey, one batch per 16 lanes.
// Direct coalesced dword global I/O (64B segments per quarter-wave) with
// nontemporal hints; single wave-private 16x17 LDS tile reused for the
// re-pass then im-pass of the mid transpose -> 17.4 KB/block, <=64 VGPR,
// 32 waves/CU. No __syncthreads anywhere (wave-private LDS + in-order
// per-wave DS ops, validated in round 3).

#define NB 16   // batches per 256-thread block
#define TS 272  // 16*17 floats per-batch tile; 272%32==16 -> sub breaks bank overlap

__device__ __forceinline__ void wave_fence() {
    __builtin_amdgcn_wave_barrier();
}

__device__ __forceinline__ void fft16(float re[16], float im[16]) {
    // 4-bit bit-reversal permutation (swap i < rev(i))
    {
        float tr, ti;
#define SWP(a, b) tr = re[a]; re[a] = re[b]; re[b] = tr; ti = im[a]; im[a] = im[b]; im[b] = ti;
        SWP(1, 8) SWP(2, 4) SWP(3, 12) SWP(5, 10) SWP(7, 14) SWP(11, 13)
#undef SWP
    }
    const float C[8] = { 1.0f,  0.92387953251f,  0.70710678119f,  0.38268343236f,
                         0.0f, -0.38268343236f, -0.70710678119f, -0.92387953251f };
    const float S16[8] = { 0.0f, -0.38268343236f, -0.70710678119f, -0.92387953251f,
                          -1.0f, -0.92387953251f, -0.70710678119f, -0.38268343236f };
#pragma unroll
    for (int s = 1; s <= 4; ++s) {
        const int len = 1 << s;
        const int half = len >> 1;
        const int step = 16 >> s;
#pragma unroll
        for (int i = 0; i < 16; i += len) {
#pragma unroll
            for (int j = 0; j < half; ++j) {
                const float wr = C[j * step];
                const float wi = S16[j * step];
                const int p = i + j;
                const int q = i + j + half;
                const float vr = re[q] * wr - im[q] * wi;
                const float vi = re[q] * wi + im[q] * wr;
                const float ur = re[p], ui = im[p];
                re[p] = ur + vr; im[p] = ui + vi;
                re[q] = ur - vr; im[q] = ui - vi;
            }
        }
    }
}

__global__ __launch_bounds__(256, 8) void fft256_kernel(const float* __restrict__ x,
                                                        float* __restrict__ out) {
    __shared__ float tile[NB * TS];

    const int tid = threadIdx.x;
    const int sub = tid >> 4;
    const int t   = tid & 15;
    const long b  = (long)blockIdx.x * NB + sub;

    const float* xr = x + b * 512;   // x[b, 0, :]
    const float* xi = xr + 256;      // x[b, 1, :]

    float re[16], im[16];

    // Load: thread t owns n1=t, stride-16 samples. Per instruction the 16
    // lanes of a sub cover a dense 64B segment -> coalesced. Nontemporal:
    // data is read exactly once.
#pragma unroll
    for (int i = 0; i < 16; ++i) re[i] = __builtin_nontemporal_load(xr + t + 16 * i);
#pragma unroll
    for (int i = 0; i < 16; ++i) im[i] = __builtin_nontemporal_load(xi + t + 16 * i);

    fft16(re, im);  // Y[t, k2] over n2

    float* L = tile + sub * TS;  // wave-private 16x17 tile

    // Twiddle W_256^{t*k}. Write imag rows to LDS now; keep real in re[]
    // (overwrite in place -> no extra 16-reg array).
#pragma unroll
    for (int k = 0; k < 16; ++k) {
        float sv, cv;
        __sincosf(-6.283185307179586f * (float)(t * k) * (1.0f / 256.0f), &sv, &cv);
        const float tr = re[k] * cv - im[k] * sv;
        const float ti = re[k] * sv + im[k] * cv;
        L[17 * t + k] = ti;
        re[k] = tr;
    }
    wave_fence();

    // Transpose pass 1: imag columns out of LDS.
#pragma unroll
    for (int n = 0; n < 16; ++n) im[n] = L[17 * n + t];
    wave_fence();

    // Transpose pass 2: real rows in, columns out (per-wave DS ops are
    // in-order, so the row-writes cannot pass the column-reads above).
#pragma unroll
    for (int k = 0; k < 16; ++k) L[17 * t + k] = re[k];
    wave_fence();
#pragma unroll
    for (int n = 0; n < 16; ++n) re[n] = L[17 * n + t];

    fft16(re, im);  // X[t + 16*k1] over k1

    float* outr = out + b * 512;
    float* outi = outr + 256;
#pragma unroll
    for (int k = 0; k < 16; ++k) __builtin_nontemporal_store(re[k], outr + t + 16 * k);
#pragma unroll
    for (int k = 0; k < 16; ++k) __builtin_nontemporal_store(im[k], outi + t + 16 * k);
}

extern "C" void kernel_launch(void* const* d_in, const int* in_sizes, int n_in,
                              void* d_out, int out_size, void* d_ws, size_t ws_size,
                              hipStream_t stream) {
    (void)d_ws; (void)ws_size; (void)n_in; (void)out_size;
    const float* x = (const float*)d_in[0];
    float* out = (float*)d_out;
    const int batches = in_sizes[0] / 512;   // 131072
    const int grid = batches / NB;           // 8192 blocks
    fft256_kernel<<<grid, 256, 0, stream>>>(x, out);
}

// Round 5
// 147.489 us; speedup vs baseline: 1.0362x; 1.0362x over previous
//
#include <hip/hip_runtime.h>
#include <math.h>

// 256-point FFT = 16x16 four-step Cooley-Tukey, one batch per 16 lanes.
// Coalesced dword global I/O (64B segments per quarter-wave). Nontemporal
// LOADS only (read-once data); PLAIN stores so L2 write-combines the
// 64B-segment stores into full 128B lines (nt stores caused 1.62x write
// amplification in round 4: WRITE_SIZE 435MB vs 268MB ideal).
// Single wave-private 16x17 LDS tile reused re-then-im -> 17.4 KB/block,
// 32 VGPR, 76% occupancy. No __syncthreads (wave-private LDS, in-order
// per-wave DS ops).

#define NB 16   // batches per 256-thread block
#define TS 272  // 16*17 floats per-batch tile

__device__ __forceinline__ void wave_fence() {
    __builtin_amdgcn_wave_barrier();
}

__device__ __forceinline__ void fft16(float re[16], float im[16]) {
    // 4-bit bit-reversal permutation (swap i < rev(i))
    {
        float tr, ti;
#define SWP(a, b) tr = re[a]; re[a] = re[b]; re[b] = tr; ti = im[a]; im[a] = im[b]; im[b] = ti;
        SWP(1, 8) SWP(2, 4) SWP(3, 12) SWP(5, 10) SWP(7, 14) SWP(11, 13)
#undef SWP
    }
    const float C[8] = { 1.0f,  0.92387953251f,  0.70710678119f,  0.38268343236f,
                         0.0f, -0.38268343236f, -0.70710678119f, -0.92387953251f };
    const float S16[8] = { 0.0f, -0.38268343236f, -0.70710678119f, -0.92387953251f,
                          -1.0f, -0.92387953251f, -0.70710678119f, -0.38268343236f };
#pragma unroll
    for (int s = 1; s <= 4; ++s) {
        const int len = 1 << s;
        const int half = len >> 1;
        const int step = 16 >> s;
#pragma unroll
        for (int i = 0; i < 16; i += len) {
#pragma unroll
            for (int j = 0; j < half; ++j) {
                const float wr = C[j * step];
                const float wi = S16[j * step];
                const int p = i + j;
                const int q = i + j + half;
                const float vr = re[q] * wr - im[q] * wi;
                const float vi = re[q] * wi + im[q] * wr;
                const float ur = re[p], ui = im[p];
                re[p] = ur + vr; im[p] = ui + vi;
                re[q] = ur - vr; im[q] = ui - vi;
            }
        }
    }
}

__global__ __launch_bounds__(256, 8) void fft256_kernel(const float* __restrict__ x,
                                                        float* __restrict__ out) {
    __shared__ float tile[NB * TS];

    const int tid = threadIdx.x;
    const int sub = tid >> 4;
    const int t   = tid & 15;
    const long b  = (long)blockIdx.x * NB + sub;

    const float* xr = x + b * 512;   // x[b, 0, :]
    const float* xi = xr + 256;      // x[b, 1, :]

    float re[16], im[16];

    // Nontemporal loads: data read exactly once; no read amplification
    // observed (FETCH <= ideal in round 4).
#pragma unroll
    for (int i = 0; i < 16; ++i) re[i] = __builtin_nontemporal_load(xr + t + 16 * i);
#pragma unroll
    for (int i = 0; i < 16; ++i) im[i] = __builtin_nontemporal_load(xi + t + 16 * i);

    fft16(re, im);  // Y[t, k2] over n2

    float* L = tile + sub * TS;  // wave-private 16x17 tile

    // Twiddle W_256^{t*k}. Imag rows to LDS now; real kept in re[].
#pragma unroll
    for (int k = 0; k < 16; ++k) {
        float sv, cv;
        __sincosf(-6.283185307179586f * (float)(t * k) * (1.0f / 256.0f), &sv, &cv);
        const float tr = re[k] * cv - im[k] * sv;
        const float ti = re[k] * sv + im[k] * cv;
        L[17 * t + k] = ti;
        re[k] = tr;
    }
    wave_fence();

    // Transpose pass 1: imag columns out.
#pragma unroll
    for (int n = 0; n < 16; ++n) im[n] = L[17 * n + t];
    wave_fence();

    // Transpose pass 2: real rows in, columns out.
#pragma unroll
    for (int k = 0; k < 16; ++k) L[17 * t + k] = re[k];
    wave_fence();
#pragma unroll
    for (int n = 0; n < 16; ++n) re[n] = L[17 * n + t];

    fft16(re, im);  // X[t + 16*k1] over k1

    // PLAIN stores -> L2 write-combines the four 64B segments per line.
    float* outr = out + b * 512;
    float* outi = outr + 256;
#pragma unroll
    for (int k = 0; k < 16; ++k) outr[t + 16 * k] = re[k];
#pragma unroll
    for (int k = 0; k < 16; ++k) outi[t + 16 * k] = im[k];
}

extern "C" void kernel_launch(void* const* d_in, const int* in_sizes, int n_in,
                              void* d_out, int out_size, void* d_ws, size_t ws_size,
                              hipStream_t stream) {
    (void)d_ws; (void)ws_size; (void)n_in; (void)out_size;
    const float* x = (const float*)d_in[0];
    float* out = (float*)d_out;
    const int batches = in_sizes[0] / 512;   // 131072
    const int grid = batches / NB;           // 8192 blocks
    fft256_kernel<<<grid, 256, 0, stream>>>(x, out);
}

// Round 6
// 97.926 us; speedup vs baseline: 1.5606x; 1.5061x over previous
//
#include <hip/hip_runtime.h>
#include <math.h>

// 256-point FFT = 16x16 four-step Cooley-Tukey, one batch per 16 lanes.
// Coalesced dword global I/O (64B segments per quarter-wave), nt loads,
// plain stores. Single wave-private 16x17 LDS tile reused re-then-im ->
// 17.4 KB/block. __launch_bounds__(256,4): round 4/5's (256,8) forced
// VGPR=32 -> scratch spills -> 1.65x WRITE amplification + 45% slowdown.
// No __syncthreads (wave-private LDS, in-order per-wave DS ops).

#define NB 16   // batches per 256-thread block
#define TS 272  // 16*17 floats per-batch tile

__device__ __forceinline__ void wave_fence() {
    __builtin_amdgcn_wave_barrier();
}

__device__ __forceinline__ void fft16(float re[16], float im[16]) {
    // 4-bit bit-reversal permutation (swap i < rev(i))
    {
        float tr, ti;
#define SWP(a, b) tr = re[a]; re[a] = re[b]; re[b] = tr; ti = im[a]; im[a] = im[b]; im[b] = ti;
        SWP(1, 8) SWP(2, 4) SWP(3, 12) SWP(5, 10) SWP(7, 14) SWP(11, 13)
#undef SWP
    }
    const float C[8] = { 1.0f,  0.92387953251f,  0.70710678119f,  0.38268343236f,
                         0.0f, -0.38268343236f, -0.70710678119f, -0.92387953251f };
    const float S16[8] = { 0.0f, -0.38268343236f, -0.70710678119f, -0.92387953251f,
                          -1.0f, -0.92387953251f, -0.70710678119f, -0.38268343236f };
#pragma unroll
    for (int s = 1; s <= 4; ++s) {
        const int len = 1 << s;
        const int half = len >> 1;
        const int step = 16 >> s;
#pragma unroll
        for (int i = 0; i < 16; i += len) {
#pragma unroll
            for (int j = 0; j < half; ++j) {
                const float wr = C[j * step];
                const float wi = S16[j * step];
                const int p = i + j;
                const int q = i + j + half;
                const float vr = re[q] * wr - im[q] * wi;
                const float vi = re[q] * wi + im[q] * wr;
                const float ur = re[p], ui = im[p];
                re[p] = ur + vr; im[p] = ui + vi;
                re[q] = ur - vr; im[q] = ui - vi;
            }
        }
    }
}

__global__ __launch_bounds__(256, 4) void fft256_kernel(const float* __restrict__ x,
                                                        float* __restrict__ out) {
    __shared__ float tile[NB * TS];

    const int tid = threadIdx.x;
    const int sub = tid >> 4;
    const int t   = tid & 15;
    const long b  = (long)blockIdx.x * NB + sub;

    const float* xr = x + b * 512;   // x[b, 0, :]
    const float* xi = xr + 256;      // x[b, 1, :]

    float re[16], im[16];

    // Nontemporal loads: read-once data; round 4/5 showed no read
    // amplification from these (FETCH <= ideal).
#pragma unroll
    for (int i = 0; i < 16; ++i) re[i] = __builtin_nontemporal_load(xr + t + 16 * i);
#pragma unroll
    for (int i = 0; i < 16; ++i) im[i] = __builtin_nontemporal_load(xi + t + 16 * i);

    fft16(re, im);  // Y[t, k2] over n2

    float* L = tile + sub * TS;  // wave-private 16x17 tile

    // Twiddle W_256^{t*k}. Imag rows to LDS now; real kept in re[].
#pragma unroll
    for (int k = 0; k < 16; ++k) {
        float sv, cv;
        __sincosf(-6.283185307179586f * (float)(t * k) * (1.0f / 256.0f), &sv, &cv);
        const float tr = re[k] * cv - im[k] * sv;
        const float ti = re[k] * sv + im[k] * cv;
        L[17 * t + k] = ti;
        re[k] = tr;
    }
    wave_fence();

    // Transpose pass 1: imag columns out.
#pragma unroll
    for (int n = 0; n < 16; ++n) im[n] = L[17 * n + t];
    wave_fence();

    // Transpose pass 2: real rows in, columns out.
#pragma unroll
    for (int k = 0; k < 16; ++k) L[17 * t + k] = re[k];
    wave_fence();
#pragma unroll
    for (int n = 0; n < 16; ++n) re[n] = L[17 * n + t];

    fft16(re, im);  // X[t + 16*k1] over k1

    // Plain stores: sequential k covers each 128B line with two adjacent
    // 64B-segment instructions -> L2 write-combines.
    float* outr = out + b * 512;
    float* outi = outr + 256;
#pragma unroll
    for (int k = 0; k < 16; ++k) outr[t + 16 * k] = re[k];
#pragma unroll
    for (int k = 0; k < 16; ++k) outi[t + 16 * k] = im[k];
}

extern "C" void kernel_launch(void* const* d_in, const int* in_sizes, int n_in,
                              void* d_out, int out_size, void* d_ws, size_t ws_size,
                              hipStream_t stream) {
    (void)d_ws; (void)ws_size; (void)n_in; (void)out_size;
    const float* x = (const float*)d_in[0];
    float* out = (float*)d_out;
    const int batches = in_sizes[0] / 512;   // 131072
    const int grid = batches / NB;           // 8192 blocks
    fft256_kernel<<<grid, 256, 0, stream>>>(x, out);
}